// Round 7
// baseline (281.579 us; speedup 1.0000x reference)
//
#include <hip/hip_runtime.h>
#include <hip/hip_bf16.h>

#define B_  8
#define C_  32
#define H_  128
#define W_  128
#define CO_ 64
#define KK_ 9
#define HW_ (H_*W_)
#define TP_ 128          // pixels per block
#define NT_ 256          // threads: 2 per pixel (channel halves), 4 waves

typedef short s16x8 __attribute__((ext_vector_type(8)));   // 8 bf16 operand
typedef float f32x4 __attribute__((ext_vector_type(4)));   // MFMA accumulator

__device__ __forceinline__ short bf16b(float f) {
    __hip_bfloat16 h = __float2bfloat16(f);
    return __builtin_bit_cast(short, h);
}

// R6: split channels across 2 thread-halves (hf = tid>>7, wave-uniform).
// Each thread: 16 channels for stage-1 partials (LDS-reduced) and gather
// (64 loads/kk instead of 128). 4 waves/block, 4 blocks/CU -> 16 waves/CU.
// Double-buffered Sl/Wl, one barrier per kk, gather(kk+1) under MFMA(kk).
__global__ __launch_bounds__(NT_, 4) void dconv_fused(
    const float* __restrict__ x,
    const float* __restrict__ w_off,
    const float* __restrict__ b_off,
    const float* __restrict__ w_mod,
    const float* __restrict__ b_mod,
    const float* __restrict__ w_reg,
    float* __restrict__ out)
{
    __shared__ float OFF[27][TP_];       // partials, then final offs/masks 13.8KB
    __shared__ short Sl[2][4][TP_][8];   // bf16 samples [buf][kg][pix][j]   16KB
    __shared__ short Wl[2][4][CO_][8];   // bf16 weights [buf][kg][o][j]      8KB

    const int tid  = threadIdx.x;
    const int p    = tid & (TP_ - 1);    // pixel within block
    const int hf   = tid >> 7;           // channel half (wave-uniform)
    const int bidx = blockIdx.x & 7;     // image == XCD (hw: XCD = blk % 8)
    const int hwbase = (blockIdx.x >> 3) * TP_;
    const int hw = hwbase + p;
    const int h  = hw / W_;
    const int w  = hw % W_;
    const float* xb = x + bidx * (C_ * HW_);
    const int c0 = hf * 16;              // my 16-channel slice

    // ---------- stage 1: partial 3x3 conv over my 16 channels --------------
    {
        float oacc[27];
        #pragma unroll
        for (int j = 0; j < 18; ++j) oacc[j] = hf ? 0.0f : b_off[j];
        #pragma unroll
        for (int j = 0; j < 9; ++j)  oacc[18 + j] = hf ? 0.0f : b_mod[j];

        for (int c = c0; c < c0 + 16; ++c) {
            float xv[9];
            #pragma unroll
            for (int t = 0; t < 9; ++t) {
                const int yy = h + t / 3 - 1;
                const int xx = w + t % 3 - 1;
                const bool ok = (yy >= 0) & (yy < H_) & (xx >= 0) & (xx < W_);
                xv[t] = ok ? xb[c * HW_ + yy * W_ + xx] : 0.0f;
            }
            const float* wo = w_off + c * 9;
            #pragma unroll
            for (int j = 0; j < 18; ++j) {
                #pragma unroll
                for (int t = 0; t < 9; ++t)
                    oacc[j] = fmaf(wo[j * (C_ * 9) + t], xv[t], oacc[j]);
            }
            const float* wm = w_mod + c * 9;
            #pragma unroll
            for (int j = 0; j < 9; ++j) {
                #pragma unroll
                for (int t = 0; t < 9; ++t)
                    oacc[18 + j] = fmaf(wm[j * (C_ * 9) + t], xv[t], oacc[18 + j]);
            }
        }
        if (hf) {                        // half 1 publishes partials
            #pragma unroll
            for (int j = 0; j < 27; ++j) OFF[j][p] = oacc[j];
        }
        __syncthreads();
        if (!hf) {                       // half 0 reduces + activates
            #pragma unroll
            for (int j = 0; j < 18; ++j)
                OFF[j][p] = fminf(fmaxf(oacc[j] + OFF[j][p], -32.0f), 32.0f);
            #pragma unroll
            for (int j = 0; j < 9; ++j)
                OFF[18 + j][p] = 2.0f / (1.0f + expf(-(oacc[18 + j] + OFF[18 + j][p])));
        }
        __syncthreads();
    }

    // ---------- helpers ----------------------------------------------------
    auto GATHER = [&](int kk2, float* sarr) {   // 16 channels -> 64 loads
        const int ky = kk2 / 3, kx = kk2 % 3;
        const float py = OFF[kk2 * 2 + 0][p] + (float)(h - 1 + ky);
        const float px = OFF[kk2 * 2 + 1][p] + (float)(w - 1 + kx);
        const float m  = OFF[18 + kk2][p];
        const float y0f = floorf(py), x0f = floorf(px);
        const float dy = py - y0f,   dx = px - x0f;
        const int y0 = (int)y0f, x0 = (int)x0f;
        const int y1 = y0 + 1,   x1 = x0 + 1;
        const bool vy0 = (y0 >= 0) & (y0 < H_);
        const bool vy1 = (y1 >= 0) & (y1 < H_);
        const bool vx0 = (x0 >= 0) & (x0 < W_);
        const bool vx1 = (x1 >= 0) & (x1 < W_);
        const float wm00 = (vy0 & vx0) ? (1.0f - dy) * (1.0f - dx) * m : 0.0f;
        const float wm01 = (vy0 & vx1) ? (1.0f - dy) * dx * m         : 0.0f;
        const float wm10 = (vy1 & vx0) ? dy * (1.0f - dx) * m         : 0.0f;
        const float wm11 = (vy1 & vx1) ? dy * dx * m                  : 0.0f;
        const int y0c = min(max(y0, 0), H_ - 1), y1c = min(max(y1, 0), H_ - 1);
        const int x0c = min(max(x0, 0), W_ - 1), x1c = min(max(x1, 0), W_ - 1);
        const int i00 = y0c * W_ + x0c, i01 = y0c * W_ + x1c;
        const int i10 = y1c * W_ + x0c, i11 = y1c * W_ + x1c;
        #pragma unroll
        for (int c4 = 0; c4 < 16; c4 += 4) {
            #pragma unroll
            for (int u = 0; u < 4; ++u) {
                const float* xc = xb + (c0 + c4 + u) * HW_;
                sarr[c4 + u] = wm00 * xc[i00] + wm01 * xc[i01]
                             + wm10 * xc[i10] + wm11 * xc[i11];
            }
        }
    };
    auto WSTAGE = [&](int kk2, s16x8* wv) {     // 1 vector per thread
        const int kg = tid >> 6, o = tid & 63;
        s16x8 t;
        #pragma unroll
        for (int j = 0; j < 8; ++j)
            t[j] = bf16b(w_reg[(o * C_ + kg * 8 + j) * 9 + kk2]);
        wv[0] = t;
    };
    auto PACK = [&](int buf, const float* sarr, const s16x8* wv) {
        #pragma unroll
        for (int u = 0; u < 2; ++u) {           // my 2 k-groups
            s16x8 v;
            #pragma unroll
            for (int j = 0; j < 8; ++j) v[j] = bf16b(sarr[u * 8 + j]);
            *(s16x8*)&Sl[buf][hf * 2 + u][p][0] = v;
        }
        const int kg = tid >> 6, o = tid & 63;
        *(s16x8*)&Wl[buf][kg][o][0] = wv[0];
    };

    // ---------- prologue: fill buffer 0 ------------------------------------
    {
        float s0[16];
        s16x8 wv0[1];
        GATHER(0, s0);
        WSTAGE(0, wv0);
        PACK(0, s0, wv0);
    }
    __syncthreads();

    const int lane = tid & 63;
    const int wid  = tid >> 6;       // 4 waves: 32-pixel slices
    const int fr   = lane & 15;
    const int fq   = lane >> 4;

    f32x4 acc[4][2];                 // [o-tile][p-tile]  (wave covers 64ox32p)
    #pragma unroll
    for (int ot = 0; ot < 4; ++ot)
        #pragma unroll
        for (int pt = 0; pt < 2; ++pt)
            acc[ot][pt] = (f32x4){0.f, 0.f, 0.f, 0.f};

    #pragma unroll
    for (int kk = 0; kk < KK_; ++kk) {
        const int cur = kk & 1, nxt = cur ^ 1;

        s16x8 af[4], bfg[2];
        #pragma unroll
        for (int ot = 0; ot < 4; ++ot)
            af[ot] = *(const s16x8*)&Wl[cur][fq][ot * 16 + fr][0];
        #pragma unroll
        for (int pt = 0; pt < 2; ++pt)
            bfg[pt] = *(const s16x8*)&Sl[cur][fq][wid * 32 + pt * 16 + fr][0];

        float sn[16];
        s16x8 wvn[1];
        if (kk + 1 < KK_) {          // issue next tile's loads under MFMA
            GATHER(kk + 1, sn);
            WSTAGE(kk + 1, wvn);
        }

        #pragma unroll
        for (int ot = 0; ot < 4; ++ot)
            #pragma unroll
            for (int pt = 0; pt < 2; ++pt)
                acc[ot][pt] = __builtin_amdgcn_mfma_f32_16x16x32_bf16(
                                  af[ot], bfg[pt], acc[ot][pt], 0, 0, 0);

        if (kk + 1 < KK_) {
            PACK(nxt, sn, wvn);
            __syncthreads();
        }
    }

    // ---------- epilogue: D lane l -> o = ot*16+fq*4+j, pix = wid*32+pt*16+fr
    float* outb = out + (size_t)bidx * (CO_ * HW_) + hwbase;
    #pragma unroll
    for (int ot = 0; ot < 4; ++ot) {
        #pragma unroll
        for (int j = 0; j < 4; ++j) {
            const int o = ot * 16 + fq * 4 + j;
            float* row = outb + o * HW_ + wid * 32 + fr;
            #pragma unroll
            for (int pt = 0; pt < 2; ++pt)
                row[pt * 16] = acc[ot][pt][j];
        }
    }
}

extern "C" void kernel_launch(void* const* d_in, const int* in_sizes, int n_in,
                              void* d_out, int out_size, void* d_ws, size_t ws_size,
                              hipStream_t stream) {
    const float* x     = (const float*)d_in[0];
    const float* w_off = (const float*)d_in[1];
    const float* b_off = (const float*)d_in[2];
    const float* w_mod = (const float*)d_in[3];
    const float* b_mod = (const float*)d_in[4];
    const float* w_reg = (const float*)d_in[5];
    float* out = (float*)d_out;
    (void)d_ws; (void)ws_size;

    dconv_fused<<<B_ * HW_ / TP_, NT_, 0, stream>>>(x, w_off, b_off, w_mod,
                                                    b_mod, w_reg, out);
}

// Round 8
// 224.705 us; speedup vs baseline: 1.2531x; 1.2531x over previous
//
#include <hip/hip_runtime.h>
#include <hip/hip_bf16.h>

#define B_  8
#define C_  32
#define H_  128
#define W_  128
#define CO_ 64
#define KK_ 9
#define HW_ (H_*W_)

typedef short s16x8 __attribute__((ext_vector_type(8)));   // 8 bf16 operand
typedef float f32x4 __attribute__((ext_vector_type(4)));   // MFMA accumulator

__device__ __forceinline__ short bf16b(float f) {
    __hip_bfloat16 h = __float2bfloat16(f);
    return __builtin_bit_cast(short, h);
}

// ---------------------------------------------------------------------------
// Kernel 1: w_reg f32 -> bf16 in A-fragment layout wb[kk][kg][o][j]
//   A lane l reads A[row=o=ot*16+(l&15)][k=(l>>4)*8+j]  (R4-verified mapping)
// ---------------------------------------------------------------------------
__global__ __launch_bounds__(256) void prep_w(const float* __restrict__ w_reg,
                                              short* __restrict__ wb)
{
    const int idx = blockIdx.x * 256 + threadIdx.x;      // 18432 elements
    const int j  = idx & 7;
    const int o  = (idx >> 3) & 63;
    const int kg = (idx >> 9) & 3;
    const int kk = idx >> 11;
    wb[idx] = bf16b(w_reg[(o * C_ + kg * 8 + j) * 9 + kk]);
}

// ---------------------------------------------------------------------------
// Kernel 2: stage-1 3x3 conv -> 18 clamped offsets + 9 sigmoid masks.
// 2 threads/pixel (channel halves, LDS-reduced) -> 1024 blocks, 16 waves/CU.
// Output layout OFF[img][27][HW] (coalesced reads in main kernel).
// ---------------------------------------------------------------------------
__global__ __launch_bounds__(256) void offsets_k(
    const float* __restrict__ x,
    const float* __restrict__ w_off,
    const float* __restrict__ b_off,
    const float* __restrict__ w_mod,
    const float* __restrict__ b_mod,
    float* __restrict__ OFF)
{
    __shared__ float red[27][128];

    const int tid = threadIdx.x;
    const int p   = tid & 127;          // pixel within chunk
    const int hf  = tid >> 7;           // channel half
    const int img = blockIdx.x & 7;     // image == XCD
    const int hwbase = (blockIdx.x >> 3) * 128;
    const int hw = hwbase + p;
    const int h  = hw / W_;
    const int w  = hw % W_;
    const float* xb = x + img * (C_ * HW_);
    const int c0 = hf * 16;

    float oacc[27];
    #pragma unroll
    for (int j = 0; j < 18; ++j) oacc[j] = hf ? 0.0f : b_off[j];
    #pragma unroll
    for (int j = 0; j < 9; ++j)  oacc[18 + j] = hf ? 0.0f : b_mod[j];

    for (int c = c0; c < c0 + 16; ++c) {
        float xv[9];
        #pragma unroll
        for (int t = 0; t < 9; ++t) {
            const int yy = h + t / 3 - 1;
            const int xx = w + t % 3 - 1;
            const bool ok = (yy >= 0) & (yy < H_) & (xx >= 0) & (xx < W_);
            xv[t] = ok ? xb[c * HW_ + yy * W_ + xx] : 0.0f;
        }
        const float* wo = w_off + c * 9;
        #pragma unroll
        for (int j = 0; j < 18; ++j) {
            #pragma unroll
            for (int t = 0; t < 9; ++t)
                oacc[j] = fmaf(wo[j * (C_ * 9) + t], xv[t], oacc[j]);
        }
        const float* wm = w_mod + c * 9;
        #pragma unroll
        for (int j = 0; j < 9; ++j) {
            #pragma unroll
            for (int t = 0; t < 9; ++t)
                oacc[18 + j] = fmaf(wm[j * (C_ * 9) + t], xv[t], oacc[18 + j]);
        }
    }

    if (hf) {                           // half 1 publishes partials
        #pragma unroll
        for (int j = 0; j < 27; ++j) red[j][p] = oacc[j];
    }
    __syncthreads();
    if (!hf) {                          // half 0 reduces, activates, stores
        float* ob = OFF + (size_t)img * 27 * HW_ + hw;
        #pragma unroll
        for (int j = 0; j < 18; ++j)
            ob[j * HW_] = fminf(fmaxf(oacc[j] + red[j][p], -32.0f), 32.0f);
        #pragma unroll
        for (int j = 0; j < 9; ++j)
            ob[(18 + j) * HW_] = 2.0f / (1.0f + expf(-(oacc[18 + j] + red[j + 18][p])));
    }
}

// ---------------------------------------------------------------------------
// Kernel 3: gather + MFMA einsum. Wave = 16 pixels x 64 outputs.
// Lane l: pixel fr=l&15, channel-group fq=l>>4 -> gathered s16x8 IS the
// MFMA B-fragment (B[k=fq*8+j][col=fr]). No LDS, no barriers.
// ---------------------------------------------------------------------------
__global__ __launch_bounds__(256, 3) void dconv_main(
    const float* __restrict__ x,
    const float* __restrict__ OFF,
    const short* __restrict__ wb,
    float* __restrict__ out)
{
    const int tid  = threadIdx.x;
    const int lane = tid & 63;
    const int wid  = tid >> 6;          // 4 waves -> 16-px slices
    const int fr   = lane & 15;         // pixel within slice
    const int fq   = lane >> 4;         // channel group (8 ch)
    const int img  = blockIdx.x & 7;    // image == XCD
    const int hwbase = (blockIdx.x >> 3) * 64 + wid * 16;   // my wave's pixels
    const int hw = hwbase + fr;
    const int h  = hw / W_;
    const int w  = hw % W_;
    const float* xb  = x + img * (C_ * HW_) + fq * 8 * HW_;
    const float* offb = OFF + (size_t)img * 27 * HW_ + hw;
    const s16x8* wbv = (const s16x8*)wb;

    f32x4 acc[4];
    #pragma unroll
    for (int ot = 0; ot < 4; ++ot) acc[ot] = (f32x4){0.f, 0.f, 0.f, 0.f};

    #pragma unroll
    for (int kk = 0; kk < KK_; ++kk) {
        const int ky = kk / 3, kx = kk % 3;
        const float offy = offb[(2 * kk + 0) * HW_];
        const float offx = offb[(2 * kk + 1) * HW_];
        const float m    = offb[(18 + kk) * HW_];

        const float py = offy + (float)(h - 1 + ky);
        const float px = offx + (float)(w - 1 + kx);
        const float y0f = floorf(py), x0f = floorf(px);
        const float dy = py - y0f,   dx = px - x0f;
        const int y0 = (int)y0f, x0 = (int)x0f;
        const int y1 = y0 + 1,   x1 = x0 + 1;
        const bool vy0 = (y0 >= 0) & (y0 < H_);
        const bool vy1 = (y1 >= 0) & (y1 < H_);
        const bool vx0 = (x0 >= 0) & (x0 < W_);
        const bool vx1 = (x1 >= 0) & (x1 < W_);
        const float wm00 = (vy0 & vx0) ? (1.0f - dy) * (1.0f - dx) * m : 0.0f;
        const float wm01 = (vy0 & vx1) ? (1.0f - dy) * dx * m         : 0.0f;
        const float wm10 = (vy1 & vx0) ? dy * (1.0f - dx) * m         : 0.0f;
        const float wm11 = (vy1 & vx1) ? dy * dx * m                  : 0.0f;
        const int y0c = min(max(y0, 0), H_ - 1), y1c = min(max(y1, 0), H_ - 1);
        const int x0c = min(max(x0, 0), W_ - 1), x1c = min(max(x1, 0), W_ - 1);
        const int i00 = y0c * W_ + x0c, i01 = y0c * W_ + x1c;
        const int i10 = y1c * W_ + x0c, i11 = y1c * W_ + x1c;

        // gather my 8 channels x 4 taps (32 independent loads)
        float s[8];
        #pragma unroll
        for (int j = 0; j < 8; ++j) {
            const float* xc = xb + j * HW_;
            s[j] = wm00 * xc[i00] + wm01 * xc[i01]
                 + wm10 * xc[i10] + wm11 * xc[i11];
        }
        s16x8 bfrag;
        #pragma unroll
        for (int j = 0; j < 8; ++j) bfrag[j] = bf16b(s[j]);

        // A-fragments straight from L2-hot bf16 weights (16B coalesced)
        s16x8 af[4];
        #pragma unroll
        for (int ot = 0; ot < 4; ++ot)
            af[ot] = wbv[(kk * 4 + fq) * 64 + ot * 16 + fr];

        #pragma unroll
        for (int ot = 0; ot < 4; ++ot)
            acc[ot] = __builtin_amdgcn_mfma_f32_16x16x32_bf16(
                          af[ot], bfrag, acc[ot], 0, 0, 0);
    }

    // D lane l: row o = ot*16 + fq*4 + i, col pix = fr  (R4-verified)
    float* outb = out + (size_t)img * (CO_ * HW_) + hwbase + fr;
    #pragma unroll
    for (int ot = 0; ot < 4; ++ot)
        #pragma unroll
        for (int i = 0; i < 4; ++i)
            outb[(ot * 16 + fq * 4 + i) * HW_] = acc[ot][i];
}

// ---------------------------------------------------------------------------
// Fallback (R5 fused kernel) if workspace is too small for the pipeline.
// ---------------------------------------------------------------------------
#define TPF_ 128
#define NTF_ 128
__global__ __launch_bounds__(NTF_, 2) void dconv_fallback(
    const float* __restrict__ x, const float* __restrict__ w_off,
    const float* __restrict__ b_off, const float* __restrict__ w_mod,
    const float* __restrict__ b_mod, const float* __restrict__ w_reg,
    float* __restrict__ out)
{
    __shared__ short Sl[2][4][TPF_][8];
    __shared__ short Wl[2][4][CO_][8];
    const int tid = threadIdx.x;
    const int bidx = blockIdx.x & 7;
    const int hwbase = (blockIdx.x >> 3) * TPF_;
    const int hw = hwbase + tid;
    const int h = hw / W_, w = hw % W_;
    const float* xb = x + bidx * (C_ * HW_);
    float oacc[27];
    #pragma unroll
    for (int j = 0; j < 18; ++j) oacc[j] = b_off[j];
    #pragma unroll
    for (int j = 0; j < 9; ++j)  oacc[18 + j] = b_mod[j];
    for (int c = 0; c < C_; ++c) {
        float xv[9];
        #pragma unroll
        for (int t = 0; t < 9; ++t) {
            const int yy = h + t / 3 - 1, xx = w + t % 3 - 1;
            const bool ok = (yy >= 0) & (yy < H_) & (xx >= 0) & (xx < W_);
            xv[t] = ok ? xb[c * HW_ + yy * W_ + xx] : 0.0f;
        }
        const float* wo = w_off + c * 9;
        #pragma unroll
        for (int j = 0; j < 18; ++j)
            #pragma unroll
            for (int t = 0; t < 9; ++t)
                oacc[j] = fmaf(wo[j * (C_ * 9) + t], xv[t], oacc[j]);
        const float* wm = w_mod + c * 9;
        #pragma unroll
        for (int j = 0; j < 9; ++j)
            #pragma unroll
            for (int t = 0; t < 9; ++t)
                oacc[18 + j] = fmaf(wm[j * (C_ * 9) + t], xv[t], oacc[18 + j]);
    }
    #pragma unroll
    for (int j = 0; j < 18; ++j) oacc[j] = fminf(fmaxf(oacc[j], -32.0f), 32.0f);
    #pragma unroll
    for (int j = 0; j < 9; ++j)  oacc[18 + j] = 2.0f / (1.0f + expf(-oacc[18 + j]));
    auto GATHER = [&](int kk2, float* sarr) {
        const int ky = kk2 / 3, kx = kk2 % 3;
        const float py = oacc[kk2 * 2] + (float)(h - 1 + ky);
        const float px = oacc[kk2 * 2 + 1] + (float)(w - 1 + kx);
        const float m = oacc[18 + kk2];
        const float y0f = floorf(py), x0f = floorf(px);
        const float dy = py - y0f, dx = px - x0f;
        const int y0 = (int)y0f, x0 = (int)x0f, y1 = y0 + 1, x1 = x0 + 1;
        const bool vy0 = (y0 >= 0) & (y0 < H_), vy1 = (y1 >= 0) & (y1 < H_);
        const bool vx0 = (x0 >= 0) & (x0 < W_), vx1 = (x1 >= 0) & (x1 < W_);
        const float wm00 = (vy0 & vx0) ? (1.0f - dy) * (1.0f - dx) * m : 0.0f;
        const float wm01 = (vy0 & vx1) ? (1.0f - dy) * dx * m : 0.0f;
        const float wm10 = (vy1 & vx0) ? dy * (1.0f - dx) * m : 0.0f;
        const float wm11 = (vy1 & vx1) ? dy * dx * m : 0.0f;
        const int y0c = min(max(y0, 0), H_ - 1), y1c = min(max(y1, 0), H_ - 1);
        const int x0c = min(max(x0, 0), W_ - 1), x1c = min(max(x1, 0), W_ - 1);
        const int i00 = y0c * W_ + x0c, i01 = y0c * W_ + x1c;
        const int i10 = y1c * W_ + x0c, i11 = y1c * W_ + x1c;
        #pragma unroll
        for (int c4 = 0; c4 < C_; c4 += 4)
            #pragma unroll
            for (int u = 0; u < 4; ++u) {
                const float* xc = xb + (c4 + u) * HW_;
                sarr[c4 + u] = wm00 * xc[i00] + wm01 * xc[i01]
                             + wm10 * xc[i10] + wm11 * xc[i11];
            }
    };
    auto WSTAGE = [&](int kk2, s16x8* wv) {
        #pragma unroll
        for (int i = 0; i < 2; ++i) {
            const int v = i * NTF_ + tid;
            const int kg = v >> 6, o = v & 63;
            s16x8 t;
            #pragma unroll
            for (int j = 0; j < 8; ++j)
                t[j] = bf16b(w_reg[(o * C_ + kg * 8 + j) * 9 + kk2]);
            wv[i] = t;
        }
    };
    auto PACK = [&](int buf, const float* sarr, const s16x8* wv) {
        #pragma unroll
        for (int kg = 0; kg < 4; ++kg) {
            s16x8 v;
            #pragma unroll
            for (int j = 0; j < 8; ++j) v[j] = bf16b(sarr[kg * 8 + j]);
            *(s16x8*)&Sl[buf][kg][tid][0] = v;
        }
        #pragma unroll
        for (int i = 0; i < 2; ++i) {
            const int v = i * NTF_ + tid;
            const int kg = v >> 6, o = v & 63;
            *(s16x8*)&Wl[buf][kg][o][0] = wv[i];
        }
    };
    { float s0[C_]; s16x8 wv0[2]; GATHER(0, s0); WSTAGE(0, wv0); PACK(0, s0, wv0); }
    __syncthreads();
    const int lane = tid & 63, wid = tid >> 6, fr = lane & 15, fq = lane >> 4;
    f32x4 acc[4][4];
    #pragma unroll
    for (int ot = 0; ot < 4; ++ot)
        #pragma unroll
        for (int pt = 0; pt < 4; ++pt) acc[ot][pt] = (f32x4){0.f,0.f,0.f,0.f};
    #pragma unroll
    for (int kk = 0; kk < KK_; ++kk) {
        const int cur = kk & 1, nxt = cur ^ 1;
        s16x8 af[4], bfg[4];
        #pragma unroll
        for (int ot = 0; ot < 4; ++ot) af[ot] = *(const s16x8*)&Wl[cur][fq][ot*16+fr][0];
        #pragma unroll
        for (int pt = 0; pt < 4; ++pt) bfg[pt] = *(const s16x8*)&Sl[cur][fq][wid*64+pt*16+fr][0];
        float sn[C_]; s16x8 wvn[2];
        if (kk + 1 < KK_) { GATHER(kk + 1, sn); WSTAGE(kk + 1, wvn); }
        #pragma unroll
        for (int ot = 0; ot < 4; ++ot)
            #pragma unroll
            for (int pt = 0; pt < 4; ++pt)
                acc[ot][pt] = __builtin_amdgcn_mfma_f32_16x16x32_bf16(af[ot], bfg[pt], acc[ot][pt], 0, 0, 0);
        if (kk + 1 < KK_) { PACK(nxt, sn, wvn); __syncthreads(); }
    }
    float* outb = out + (size_t)bidx * (CO_ * HW_) + hwbase;
    #pragma unroll
    for (int ot = 0; ot < 4; ++ot)
        #pragma unroll
        for (int j = 0; j < 4; ++j) {
            const int o = ot * 16 + fq * 4 + j;
            float* row = outb + o * HW_ + wid * 64 + fr;
            #pragma unroll
            for (int pt = 0; pt < 4; ++pt) row[pt * 16] = acc[ot][pt][j];
        }
}

extern "C" void kernel_launch(void* const* d_in, const int* in_sizes, int n_in,
                              void* d_out, int out_size, void* d_ws, size_t ws_size,
                              hipStream_t stream) {
    const float* x     = (const float*)d_in[0];
    const float* w_off = (const float*)d_in[1];
    const float* b_off = (const float*)d_in[2];
    const float* w_mod = (const float*)d_in[3];
    const float* b_mod = (const float*)d_in[4];
    const float* w_reg = (const float*)d_in[5];
    float* out = (float*)d_out;

    const size_t WB_BYTES  = 9 * 4 * 64 * 8 * sizeof(short);   // 36 KB
    const size_t OFF_OFFS  = 65536;                            // align
    const size_t OFF_BYTES = (size_t)B_ * 27 * HW_ * sizeof(float);  // 14.2 MB

    if (ws_size >= OFF_OFFS + OFF_BYTES) {
        short* wb  = (short*)d_ws;
        float* OFF = (float*)((char*)d_ws + OFF_OFFS);
        prep_w<<<(9 * 4 * 64 * 8) / 256, 256, 0, stream>>>(w_reg, wb);
        offsets_k<<<B_ * HW_ / 128, 256, 0, stream>>>(x, w_off, b_off,
                                                      w_mod, b_mod, OFF);
        dconv_main<<<B_ * HW_ / 64, 256, 0, stream>>>(x, OFF, wb, out);
        (void)WB_BYTES;
    } else {
        dconv_fallback<<<B_ * HW_ / TPF_, NTF_, 0, stream>>>(
            x, w_off, b_off, w_mod, b_mod, w_reg, out);
    }
}

// Round 9
// 124.393 us; speedup vs baseline: 2.2636x; 1.8064x over previous
//
#include <hip/hip_runtime.h>
#include <hip/hip_bf16.h>

#define B_  8
#define C_  32
#define H_  128
#define W_  128
#define CO_ 64
#define KK_ 9
#define HW_ (H_*W_)

typedef short s16x8 __attribute__((ext_vector_type(8)));   // 8 bf16 operand
typedef float f32x4 __attribute__((ext_vector_type(4)));   // MFMA accumulator

__device__ __forceinline__ short bf16b(float f) {
    __hip_bfloat16 h = __float2bfloat16(f);
    return __builtin_bit_cast(short, h);
}

// ---------------------------------------------------------------------------
// Kernel 1a: w_reg f32 -> bf16 A-fragment layout wb[kk][kg][o(64)][j]
// ---------------------------------------------------------------------------
__global__ __launch_bounds__(256) void prep_w(const float* __restrict__ w_reg,
                                              short* __restrict__ wb)
{
    const int idx = blockIdx.x * 256 + threadIdx.x;      // 18432 elements
    const int j  = idx & 7;
    const int o  = (idx >> 3) & 63;
    const int kg = (idx >> 9) & 3;
    const int kk = idx >> 11;
    wb[idx] = bf16b(w_reg[(o * C_ + kg * 8 + j) * 9 + kk]);
}

// ---------------------------------------------------------------------------
// Kernel 1b: w_off(18 rows) || w_mod(9 rows) || zeros(5) -> bf16 A-fragment
// layout wof[kk][kg][row(32)][j].  Row r of the stage-1 "GEMM": r<18 offsets,
// 18..26 masks, 27..31 zero-padding.
// ---------------------------------------------------------------------------
__global__ __launch_bounds__(256) void prep_wof(const float* __restrict__ w_off,
                                                const float* __restrict__ w_mod,
                                                short* __restrict__ wof)
{
    const int idx = blockIdx.x * 256 + threadIdx.x;      // 9216 elements
    const int j   = idx & 7;
    const int row = (idx >> 3) & 31;
    const int kg  = (idx >> 8) & 3;
    const int kk  = idx >> 10;
    const int c   = kg * 8 + j;
    float v = 0.0f;
    if (row < 18)      v = w_off[(row * C_ + c) * 9 + kk];
    else if (row < 27) v = w_mod[((row - 18) * C_ + c) * 9 + kk];
    wof[idx] = bf16b(v);
}

// ---------------------------------------------------------------------------
// Kernel 2: stage-1 3x3 conv on the MATRIX pipe.
// OFF[27 x HW] = Wcat[27 x 288] * im2col(x)[288 x HW], K split as 9 taps x 32ch.
// Wave = 16 pixels; lane(fq,fr): B-frag for tap t = x[fq*8+j][pix_fr shifted
// by t] (plain shifted loads) -> 8 loads + 2 MFMA per tap, no LDS/barriers.
// Epilogue: clamp rows 0..17, 2*sigmoid rows 18..26. Output OFF[img][27][HW].
// ---------------------------------------------------------------------------
__global__ __launch_bounds__(256, 4) void offsets_mfma(
    const float* __restrict__ x,
    const float* __restrict__ b_off,
    const float* __restrict__ b_mod,
    const short* __restrict__ wof,
    float* __restrict__ OFF)
{
    const int tid  = threadIdx.x;
    const int lane = tid & 63;
    const int wid  = tid >> 6;
    const int fr   = lane & 15;         // pixel within wave slice
    const int fq   = lane >> 4;         // channel group
    const int img  = blockIdx.x & 7;    // image == XCD
    const int hwbase = (blockIdx.x >> 3) * 64 + wid * 16;
    const int hw = hwbase + fr;
    const int h  = hw / W_;
    const int w  = hw % W_;
    const float* xc = x + img * (C_ * HW_) + fq * 8 * HW_;
    const s16x8* wofv = (const s16x8*)wof;

    f32x4 acc[2];
    acc[0] = (f32x4){0.f, 0.f, 0.f, 0.f};
    acc[1] = (f32x4){0.f, 0.f, 0.f, 0.f};

    #pragma unroll
    for (int t = 0; t < 9; ++t) {
        const int yy = h + t / 3 - 1;
        const int xx = w + t % 3 - 1;
        const bool ok = (yy >= 0) & (yy < H_) & (xx >= 0) & (xx < W_);
        const int idx = yy * W_ + xx;

        s16x8 bfrag;
        #pragma unroll
        for (int j = 0; j < 8; ++j) {
            const float v = ok ? xc[j * HW_ + idx] : 0.0f;
            bfrag[j] = bf16b(v);
        }
        s16x8 af0 = wofv[(t * 4 + fq) * 32 + fr];
        s16x8 af1 = wofv[(t * 4 + fq) * 32 + 16 + fr];
        acc[0] = __builtin_amdgcn_mfma_f32_16x16x32_bf16(af0, bfrag, acc[0], 0, 0, 0);
        acc[1] = __builtin_amdgcn_mfma_f32_16x16x32_bf16(af1, bfrag, acc[1], 0, 0, 0);
    }

    // D lane l: row o = ot*16 + fq*4 + i, col = fr.  Add bias, activate, store.
    float* ob = OFF + (size_t)img * 27 * HW_ + hw;
    #pragma unroll
    for (int ot = 0; ot < 2; ++ot) {
        #pragma unroll
        for (int i = 0; i < 4; ++i) {
            const int o = ot * 16 + fq * 4 + i;
            if (o < 18) {
                const float v = acc[ot][i] + b_off[o];
                ob[o * HW_] = fminf(fmaxf(v, -32.0f), 32.0f);
            } else if (o < 27) {
                const float v = acc[ot][i] + b_mod[o - 18];
                ob[o * HW_] = 2.0f / (1.0f + expf(-v));
            }
        }
    }
}

// ---------------------------------------------------------------------------
// Kernel 3: gather + MFMA einsum (unchanged from R7). Wave = 16 px x 64 out.
// ---------------------------------------------------------------------------
__global__ __launch_bounds__(256, 3) void dconv_main(
    const float* __restrict__ x,
    const float* __restrict__ OFF,
    const short* __restrict__ wb,
    float* __restrict__ out)
{
    const int tid  = threadIdx.x;
    const int lane = tid & 63;
    const int wid  = tid >> 6;
    const int fr   = lane & 15;
    const int fq   = lane >> 4;
    const int img  = blockIdx.x & 7;
    const int hwbase = (blockIdx.x >> 3) * 64 + wid * 16;
    const int hw = hwbase + fr;
    const int h  = hw / W_;
    const int w  = hw % W_;
    const float* xb  = x + img * (C_ * HW_) + fq * 8 * HW_;
    const float* offb = OFF + (size_t)img * 27 * HW_ + hw;
    const s16x8* wbv = (const s16x8*)wb;

    f32x4 acc[4];
    #pragma unroll
    for (int ot = 0; ot < 4; ++ot) acc[ot] = (f32x4){0.f, 0.f, 0.f, 0.f};

    #pragma unroll
    for (int kk = 0; kk < KK_; ++kk) {
        const int ky = kk / 3, kx = kk % 3;
        const float offy = offb[(2 * kk + 0) * HW_];
        const float offx = offb[(2 * kk + 1) * HW_];
        const float m    = offb[(18 + kk) * HW_];

        const float py = offy + (float)(h - 1 + ky);
        const float px = offx + (float)(w - 1 + kx);
        const float y0f = floorf(py), x0f = floorf(px);
        const float dy = py - y0f,   dx = px - x0f;
        const int y0 = (int)y0f, x0 = (int)x0f;
        const int y1 = y0 + 1,   x1 = x0 + 1;
        const bool vy0 = (y0 >= 0) & (y0 < H_);
        const bool vy1 = (y1 >= 0) & (y1 < H_);
        const bool vx0 = (x0 >= 0) & (x0 < W_);
        const bool vx1 = (x1 >= 0) & (x1 < W_);
        const float wm00 = (vy0 & vx0) ? (1.0f - dy) * (1.0f - dx) * m : 0.0f;
        const float wm01 = (vy0 & vx1) ? (1.0f - dy) * dx * m         : 0.0f;
        const float wm10 = (vy1 & vx0) ? dy * (1.0f - dx) * m         : 0.0f;
        const float wm11 = (vy1 & vx1) ? dy * dx * m                  : 0.0f;
        const int y0c = min(max(y0, 0), H_ - 1), y1c = min(max(y1, 0), H_ - 1);
        const int x0c = min(max(x0, 0), W_ - 1), x1c = min(max(x1, 0), W_ - 1);
        const int i00 = y0c * W_ + x0c, i01 = y0c * W_ + x1c;
        const int i10 = y1c * W_ + x0c, i11 = y1c * W_ + x1c;

        float s[8];
        #pragma unroll
        for (int j = 0; j < 8; ++j) {
            const float* xc = xb + j * HW_;
            s[j] = wm00 * xc[i00] + wm01 * xc[i01]
                 + wm10 * xc[i10] + wm11 * xc[i11];
        }
        s16x8 bfrag;
        #pragma unroll
        for (int j = 0; j < 8; ++j) bfrag[j] = bf16b(s[j]);

        s16x8 af[4];
        #pragma unroll
        for (int ot = 0; ot < 4; ++ot)
            af[ot] = wbv[(kk * 4 + fq) * 64 + ot * 16 + fr];

        #pragma unroll
        for (int ot = 0; ot < 4; ++ot)
            acc[ot] = __builtin_amdgcn_mfma_f32_16x16x32_bf16(
                          af[ot], bfrag, acc[ot], 0, 0, 0);
    }

    float* outb = out + (size_t)img * (CO_ * HW_) + hwbase + fr;
    #pragma unroll
    for (int ot = 0; ot < 4; ++ot)
        #pragma unroll
        for (int i = 0; i < 4; ++i)
            outb[(ot * 16 + fq * 4 + i) * HW_] = acc[ot][i];
}

// ---------------------------------------------------------------------------
// Fallback (R5 fused kernel) if workspace is too small for the pipeline.
// ---------------------------------------------------------------------------
#define TPF_ 128
#define NTF_ 128
__global__ __launch_bounds__(NTF_, 2) void dconv_fallback(
    const float* __restrict__ x, const float* __restrict__ w_off,
    const float* __restrict__ b_off, const float* __restrict__ w_mod,
    const float* __restrict__ b_mod, const float* __restrict__ w_reg,
    float* __restrict__ out)
{
    __shared__ short Sl[2][4][TPF_][8];
    __shared__ short Wl[2][4][CO_][8];
    const int tid = threadIdx.x;
    const int bidx = blockIdx.x & 7;
    const int hwbase = (blockIdx.x >> 3) * TPF_;
    const int hw = hwbase + tid;
    const int h = hw / W_, w = hw % W_;
    const float* xb = x + bidx * (C_ * HW_);
    float oacc[27];
    #pragma unroll
    for (int j = 0; j < 18; ++j) oacc[j] = b_off[j];
    #pragma unroll
    for (int j = 0; j < 9; ++j)  oacc[18 + j] = b_mod[j];
    for (int c = 0; c < C_; ++c) {
        float xv[9];
        #pragma unroll
        for (int t = 0; t < 9; ++t) {
            const int yy = h + t / 3 - 1, xx = w + t % 3 - 1;
            const bool ok = (yy >= 0) & (yy < H_) & (xx >= 0) & (xx < W_);
            xv[t] = ok ? xb[c * HW_ + yy * W_ + xx] : 0.0f;
        }
        const float* wo = w_off + c * 9;
        #pragma unroll
        for (int j = 0; j < 18; ++j)
            #pragma unroll
            for (int t = 0; t < 9; ++t)
                oacc[j] = fmaf(wo[j * (C_ * 9) + t], xv[t], oacc[j]);
        const float* wm = w_mod + c * 9;
        #pragma unroll
        for (int j = 0; j < 9; ++j)
            #pragma unroll
            for (int t = 0; t < 9; ++t)
                oacc[18 + j] = fmaf(wm[j * (C_ * 9) + t], xv[t], oacc[18 + j]);
    }
    #pragma unroll
    for (int j = 0; j < 18; ++j) oacc[j] = fminf(fmaxf(oacc[j], -32.0f), 32.0f);
    #pragma unroll
    for (int j = 0; j < 9; ++j)  oacc[18 + j] = 2.0f / (1.0f + expf(-oacc[18 + j]));
    auto GATHER = [&](int kk2, float* sarr) {
        const int ky = kk2 / 3, kx = kk2 % 3;
        const float py = oacc[kk2 * 2] + (float)(h - 1 + ky);
        const float px = oacc[kk2 * 2 + 1] + (float)(w - 1 + kx);
        const float m = oacc[18 + kk2];
        const float y0f = floorf(py), x0f = floorf(px);
        const float dy = py - y0f, dx = px - x0f;
        const int y0 = (int)y0f, x0 = (int)x0f, y1 = y0 + 1, x1 = x0 + 1;
        const bool vy0 = (y0 >= 0) & (y0 < H_), vy1 = (y1 >= 0) & (y1 < H_);
        const bool vx0 = (x0 >= 0) & (x0 < W_), vx1 = (x1 >= 0) & (x1 < W_);
        const float wm00 = (vy0 & vx0) ? (1.0f - dy) * (1.0f - dx) * m : 0.0f;
        const float wm01 = (vy0 & vx1) ? (1.0f - dy) * dx * m : 0.0f;
        const float wm10 = (vy1 & vx0) ? dy * (1.0f - dx) * m : 0.0f;
        const float wm11 = (vy1 & vx1) ? dy * dx * m : 0.0f;
        const int y0c = min(max(y0, 0), H_ - 1), y1c = min(max(y1, 0), H_ - 1);
        const int x0c = min(max(x0, 0), W_ - 1), x1c = min(max(x1, 0), W_ - 1);
        const int i00 = y0c * W_ + x0c, i01 = y0c * W_ + x1c;
        const int i10 = y1c * W_ + x0c, i11 = y1c * W_ + x1c;
        #pragma unroll
        for (int c4 = 0; c4 < C_; c4 += 4)
            #pragma unroll
            for (int u = 0; u < 4; ++u) {
                const float* xc = xb + (c4 + u) * HW_;
                sarr[c4 + u] = wm00 * xc[i00] + wm01 * xc[i01]
                             + wm10 * xc[i10] + wm11 * xc[i11];
            }
    };
    auto WSTAGE = [&](int kk2, s16x8* wv) {
        #pragma unroll
        for (int i = 0; i < 2; ++i) {
            const int v = i * NTF_ + tid;
            const int kg = v >> 6, o = v & 63;
            s16x8 t;
            #pragma unroll
            for (int j = 0; j < 8; ++j)
                t[j] = bf16b(w_reg[(o * C_ + kg * 8 + j) * 9 + kk2]);
            wv[i] = t;
        }
    };
    auto PACK = [&](int buf, const float* sarr, const s16x8* wv) {
        #pragma unroll
        for (int kg = 0; kg < 4; ++kg) {
            s16x8 v;
            #pragma unroll
            for (int j = 0; j < 8; ++j) v[j] = bf16b(sarr[kg * 8 + j]);
            *(s16x8*)&Sl[buf][kg][tid][0] = v;
        }
        #pragma unroll
        for (int i = 0; i < 2; ++i) {
            const int v = i * NTF_ + tid;
            const int kg = v >> 6, o = v & 63;
            *(s16x8*)&Wl[buf][kg][o][0] = wv[i];
        }
    };
    { float s0[C_]; s16x8 wv0[2]; GATHER(0, s0); WSTAGE(0, wv0); PACK(0, s0, wv0); }
    __syncthreads();
    const int lane = tid & 63, wid = tid >> 6, fr = lane & 15, fq = lane >> 4;
    f32x4 acc[4][4];
    #pragma unroll
    for (int ot = 0; ot < 4; ++ot)
        #pragma unroll
        for (int pt = 0; pt < 4; ++pt) acc[ot][pt] = (f32x4){0.f,0.f,0.f,0.f};
    #pragma unroll
    for (int kk = 0; kk < KK_; ++kk) {
        const int cur = kk & 1, nxt = cur ^ 1;
        s16x8 af[4], bfg[4];
        #pragma unroll
        for (int ot = 0; ot < 4; ++ot) af[ot] = *(const s16x8*)&Wl[cur][fq][ot*16+fr][0];
        #pragma unroll
        for (int pt = 0; pt < 4; ++pt) bfg[pt] = *(const s16x8*)&Sl[cur][fq][wid*64+pt*16+fr][0];
        float sn[C_]; s16x8 wvn[2];
        if (kk + 1 < KK_) { GATHER(kk + 1, sn); WSTAGE(kk + 1, wvn); }
        #pragma unroll
        for (int ot = 0; ot < 4; ++ot)
            #pragma unroll
            for (int pt = 0; pt < 4; ++pt)
                acc[ot][pt] = __builtin_amdgcn_mfma_f32_16x16x32_bf16(af[ot], bfg[pt], acc[ot][pt], 0, 0, 0);
        if (kk + 1 < KK_) { PACK(nxt, sn, wvn); __syncthreads(); }
    }
    float* outb = out + (size_t)bidx * (CO_ * HW_) + hwbase;
    #pragma unroll
    for (int ot = 0; ot < 4; ++ot)
        #pragma unroll
        for (int j = 0; j < 4; ++j) {
            const int o = ot * 16 + fq * 4 + j;
            float* row = outb + o * HW_ + wid * 64 + fr;
            #pragma unroll
            for (int pt = 0; pt < 4; ++pt) row[pt * 16] = acc[ot][pt][j];
        }
}

extern "C" void kernel_launch(void* const* d_in, const int* in_sizes, int n_in,
                              void* d_out, int out_size, void* d_ws, size_t ws_size,
                              hipStream_t stream) {
    const float* x     = (const float*)d_in[0];
    const float* w_off = (const float*)d_in[1];
    const float* b_off = (const float*)d_in[2];
    const float* w_mod = (const float*)d_in[3];
    const float* b_mod = (const float*)d_in[4];
    const float* w_reg = (const float*)d_in[5];
    float* out = (float*)d_out;

    const size_t WOF_OFFS  = 36864;                            // after wb (36KB)
    const size_t OFF_OFFS  = 65536;
    const size_t OFF_BYTES = (size_t)B_ * 27 * HW_ * sizeof(float);  // 14.2 MB

    if (ws_size >= OFF_OFFS + OFF_BYTES) {
        short* wb  = (short*)d_ws;
        short* wof = (short*)((char*)d_ws + WOF_OFFS);
        float* OFF = (float*)((char*)d_ws + OFF_OFFS);
        prep_w  <<<(9 * 4 * 64 * 8) / 256, 256, 0, stream>>>(w_reg, wb);
        prep_wof<<<(9 * 4 * 32 * 8) / 256, 256, 0, stream>>>(w_off, w_mod, wof);
        offsets_mfma<<<B_ * HW_ / 64, 256, 0, stream>>>(x, b_off, b_mod, wof, OFF);
        dconv_main  <<<B_ * HW_ / 64, 256, 0, stream>>>(x, OFF, wb, out);
    } else {
        dconv_fallback<<<B_ * HW_ / TPF_, NTF_, 0, stream>>>(
            x, w_off, b_off, w_mod, b_mod, w_reg, out);
    }
}

// Round 10
// 66.334 us; speedup vs baseline: 4.2448x; 1.8752x over previous
//
#include <hip/hip_runtime.h>
#include <hip/hip_bf16.h>

#define B_  8
#define C_  32
#define H_  128
#define W_  128
#define CO_ 64
#define KK_ 9
#define HW_ (H_*W_)

typedef short s16x8 __attribute__((ext_vector_type(8)));   // 8 bf16 operand
typedef float f32x4 __attribute__((ext_vector_type(4)));   // MFMA accumulator

__device__ __forceinline__ short bf16b(float f) {
    __hip_bfloat16 h = __float2bfloat16(f);
    return __builtin_bit_cast(short, h);
}
__device__ __forceinline__ float bf2f(short s) {
    unsigned u = ((unsigned)(unsigned short)s) << 16;
    return __builtin_bit_cast(float, u);
}

// ---------------------------------------------------------------------------
// Kernel 1a: w_reg f32 -> bf16 A-fragment layout wb[kk][kg][o(64)][j]
// ---------------------------------------------------------------------------
__global__ __launch_bounds__(256) void prep_w(const float* __restrict__ w_reg,
                                              short* __restrict__ wb)
{
    const int idx = blockIdx.x * 256 + threadIdx.x;      // 18432 elements
    const int j  = idx & 7;
    const int o  = (idx >> 3) & 63;
    const int kg = (idx >> 9) & 3;
    const int kk = idx >> 11;
    wb[idx] = bf16b(w_reg[(o * C_ + kg * 8 + j) * 9 + kk]);
}

// ---------------------------------------------------------------------------
// Kernel 1b: w_off(18) || w_mod(9) || zeros(5) -> bf16 A-frag wof[kk][kg][32][j]
// ---------------------------------------------------------------------------
__global__ __launch_bounds__(256) void prep_wof(const float* __restrict__ w_off,
                                                const float* __restrict__ w_mod,
                                                short* __restrict__ wof)
{
    const int idx = blockIdx.x * 256 + threadIdx.x;      // 9216 elements
    const int j   = idx & 7;
    const int row = (idx >> 3) & 31;
    const int kg  = (idx >> 8) & 3;
    const int kk  = idx >> 10;
    const int c   = kg * 8 + j;
    float v = 0.0f;
    if (row < 18)      v = w_off[(row * C_ + c) * 9 + kk];
    else if (row < 27) v = w_mod[((row - 18) * C_ + c) * 9 + kk];
    wof[idx] = bf16b(v);
}

// ---------------------------------------------------------------------------
// Kernel 1c: transpose x f32[img][32][HW] -> xt bf16[img][HW][32].
// Reads coalesced (lane = pixel, loop c), writes contiguous 64B per lane.
// One pixel's 32 channels = one 64B cacheline -> gather taps become 16B loads.
// ---------------------------------------------------------------------------
__global__ __launch_bounds__(256) void prep_xt(const float* __restrict__ x,
                                               short* __restrict__ xt)
{
    const int img = blockIdx.x & 7;
    const int pix = (blockIdx.x >> 3) * 256 + threadIdx.x;
    const float* xb = x + img * (C_ * HW_);
    short v[C_];
    #pragma unroll
    for (int c = 0; c < C_; ++c) v[c] = bf16b(xb[c * HW_ + pix]);
    short* dst = xt + ((size_t)img * HW_ + pix) * C_;
    #pragma unroll
    for (int q = 0; q < 4; ++q)
        *(s16x8*)(dst + q * 8) = *(s16x8*)&v[q * 8];
}

// ---------------------------------------------------------------------------
// Kernel 2: stage-1 3x3 conv on the MATRIX pipe, B-frags straight from xt.
// Per tap: ONE 16B load + 2 MFMA. Output OFF[img][27][HW] (f32).
// ---------------------------------------------------------------------------
__global__ __launch_bounds__(256, 4) void offsets_mfma(
    const short* __restrict__ xt,
    const float* __restrict__ b_off,
    const float* __restrict__ b_mod,
    const short* __restrict__ wof,
    float* __restrict__ OFF)
{
    const int tid  = threadIdx.x;
    const int lane = tid & 63;
    const int wid  = tid >> 6;
    const int fr   = lane & 15;         // pixel within wave slice
    const int fq   = lane >> 4;         // channel group
    const int img  = blockIdx.x & 7;    // image == XCD
    const int hwbase = (blockIdx.x >> 3) * 64 + wid * 16;
    const int hw = hwbase + fr;
    const int h  = hw / W_;
    const int w  = hw % W_;
    const short* xtb = xt + (size_t)img * HW_ * C_;
    const s16x8* wofv = (const s16x8*)wof;

    f32x4 acc[2];
    acc[0] = (f32x4){0.f, 0.f, 0.f, 0.f};
    acc[1] = (f32x4){0.f, 0.f, 0.f, 0.f};
    const s16x8 zf = (s16x8){0,0,0,0,0,0,0,0};

    #pragma unroll
    for (int t = 0; t < 9; ++t) {
        const int yy = h + t / 3 - 1;
        const int xx = w + t % 3 - 1;
        const bool ok = (yy >= 0) & (yy < H_) & (xx >= 0) & (xx < W_);
        const int idx = yy * W_ + xx;

        const s16x8 bfrag = ok ? *(const s16x8*)&xtb[idx * C_ + fq * 8] : zf;
        s16x8 af0 = wofv[(t * 4 + fq) * 32 + fr];
        s16x8 af1 = wofv[(t * 4 + fq) * 32 + 16 + fr];
        acc[0] = __builtin_amdgcn_mfma_f32_16x16x32_bf16(af0, bfrag, acc[0], 0, 0, 0);
        acc[1] = __builtin_amdgcn_mfma_f32_16x16x32_bf16(af1, bfrag, acc[1], 0, 0, 0);
    }

    float* ob = OFF + (size_t)img * 27 * HW_ + hw;
    #pragma unroll
    for (int ot = 0; ot < 2; ++ot) {
        #pragma unroll
        for (int i = 0; i < 4; ++i) {
            const int o = ot * 16 + fq * 4 + i;
            if (o < 18) {
                const float v = acc[ot][i] + b_off[o];
                ob[o * HW_] = fminf(fmaxf(v, -32.0f), 32.0f);
            } else if (o < 27) {
                const float v = acc[ot][i] + b_mod[o - 18];
                ob[o * HW_] = 2.0f / (1.0f + expf(-v));
            }
        }
    }
}

// ---------------------------------------------------------------------------
// Kernel 3: gather (16B/tap from xt) + bilinear on VALU + MFMA einsum.
// Wave = 16 px x 64 out. Per kk/lane: 4x16B taps + 3 OFF + 4 wb loads, 4 MFMA.
// ---------------------------------------------------------------------------
__global__ __launch_bounds__(256, 4) void dconv_main(
    const short* __restrict__ xt,
    const float* __restrict__ OFF,
    const short* __restrict__ wb,
    float* __restrict__ out)
{
    const int tid  = threadIdx.x;
    const int lane = tid & 63;
    const int wid  = tid >> 6;
    const int fr   = lane & 15;
    const int fq   = lane >> 4;
    const int img  = blockIdx.x & 7;
    const int hwbase = (blockIdx.x >> 3) * 64 + wid * 16;
    const int hw = hwbase + fr;
    const int h  = hw / W_;
    const int w  = hw % W_;
    const short* xtb  = xt + (size_t)img * HW_ * C_ + fq * 8;
    const float* offb = OFF + (size_t)img * 27 * HW_ + hw;
    const s16x8* wbv = (const s16x8*)wb;

    f32x4 acc[4];
    #pragma unroll
    for (int ot = 0; ot < 4; ++ot) acc[ot] = (f32x4){0.f, 0.f, 0.f, 0.f};

    #pragma unroll
    for (int kk = 0; kk < KK_; ++kk) {
        const int ky = kk / 3, kx = kk % 3;
        const float offy = offb[(2 * kk + 0) * HW_];
        const float offx = offb[(2 * kk + 1) * HW_];
        const float m    = offb[(18 + kk) * HW_];

        const float py = offy + (float)(h - 1 + ky);
        const float px = offx + (float)(w - 1 + kx);
        const float y0f = floorf(py), x0f = floorf(px);
        const float dy = py - y0f,   dx = px - x0f;
        const int y0 = (int)y0f, x0 = (int)x0f;
        const int y1 = y0 + 1,   x1 = x0 + 1;
        const bool vy0 = (y0 >= 0) & (y0 < H_);
        const bool vy1 = (y1 >= 0) & (y1 < H_);
        const bool vx0 = (x0 >= 0) & (x0 < W_);
        const bool vx1 = (x1 >= 0) & (x1 < W_);
        const float wm00 = (vy0 & vx0) ? (1.0f - dy) * (1.0f - dx) * m : 0.0f;
        const float wm01 = (vy0 & vx1) ? (1.0f - dy) * dx * m         : 0.0f;
        const float wm10 = (vy1 & vx0) ? dy * (1.0f - dx) * m         : 0.0f;
        const float wm11 = (vy1 & vx1) ? dy * dx * m                  : 0.0f;
        const int y0c = min(max(y0, 0), H_ - 1), y1c = min(max(y1, 0), H_ - 1);
        const int x0c = min(max(x0, 0), W_ - 1), x1c = min(max(x1, 0), W_ - 1);

        // 4 taps, ONE 16B load each (8 channels, bf16, aligned)
        const s16x8 v00 = *(const s16x8*)&xtb[(y0c * W_ + x0c) * C_];
        const s16x8 v01 = *(const s16x8*)&xtb[(y0c * W_ + x1c) * C_];
        const s16x8 v10 = *(const s16x8*)&xtb[(y1c * W_ + x0c) * C_];
        const s16x8 v11 = *(const s16x8*)&xtb[(y1c * W_ + x1c) * C_];

        s16x8 bfrag;
        #pragma unroll
        for (int j = 0; j < 8; ++j) {
            const float s = wm00 * bf2f(v00[j]) + wm01 * bf2f(v01[j])
                          + wm10 * bf2f(v10[j]) + wm11 * bf2f(v11[j]);
            bfrag[j] = bf16b(s);
        }

        s16x8 af[4];
        #pragma unroll
        for (int ot = 0; ot < 4; ++ot)
            af[ot] = wbv[(kk * 4 + fq) * 64 + ot * 16 + fr];

        #pragma unroll
        for (int ot = 0; ot < 4; ++ot)
            acc[ot] = __builtin_amdgcn_mfma_f32_16x16x32_bf16(
                          af[ot], bfrag, acc[ot], 0, 0, 0);
    }

    float* outb = out + (size_t)img * (CO_ * HW_) + hwbase + fr;
    #pragma unroll
    for (int ot = 0; ot < 4; ++ot)
        #pragma unroll
        for (int i = 0; i < 4; ++i)
            outb[(ot * 16 + fq * 4 + i) * HW_] = acc[ot][i];
}

// ---------------------------------------------------------------------------
// Fallback (R5 fused kernel) if workspace is too small for the pipeline.
// ---------------------------------------------------------------------------
#define TPF_ 128
#define NTF_ 128
__global__ __launch_bounds__(NTF_, 2) void dconv_fallback(
    const float* __restrict__ x, const float* __restrict__ w_off,
    const float* __restrict__ b_off, const float* __restrict__ w_mod,
    const float* __restrict__ b_mod, const float* __restrict__ w_reg,
    float* __restrict__ out)
{
    __shared__ short Sl[2][4][TPF_][8];
    __shared__ short Wl[2][4][CO_][8];
    const int tid = threadIdx.x;
    const int bidx = blockIdx.x & 7;
    const int hwbase = (blockIdx.x >> 3) * TPF_;
    const int hw = hwbase + tid;
    const int h = hw / W_, w = hw % W_;
    const float* xb = x + bidx * (C_ * HW_);
    float oacc[27];
    #pragma unroll
    for (int j = 0; j < 18; ++j) oacc[j] = b_off[j];
    #pragma unroll
    for (int j = 0; j < 9; ++j)  oacc[18 + j] = b_mod[j];
    for (int c = 0; c < C_; ++c) {
        float xv[9];
        #pragma unroll
        for (int t = 0; t < 9; ++t) {
            const int yy = h + t / 3 - 1, xx = w + t % 3 - 1;
            const bool ok = (yy >= 0) & (yy < H_) & (xx >= 0) & (xx < W_);
            xv[t] = ok ? xb[c * HW_ + yy * W_ + xx] : 0.0f;
        }
        const float* wo = w_off + c * 9;
        #pragma unroll
        for (int j = 0; j < 18; ++j)
            #pragma unroll
            for (int t = 0; t < 9; ++t)
                oacc[j] = fmaf(wo[j * (C_ * 9) + t], xv[t], oacc[j]);
        const float* wm = w_mod + c * 9;
        #pragma unroll
        for (int j = 0; j < 9; ++j)
            #pragma unroll
            for (int t = 0; t < 9; ++t)
                oacc[18 + j] = fmaf(wm[j * (C_ * 9) + t], xv[t], oacc[18 + j]);
    }
    #pragma unroll
    for (int j = 0; j < 18; ++j) oacc[j] = fminf(fmaxf(oacc[j], -32.0f), 32.0f);
    #pragma unroll
    for (int j = 0; j < 9; ++j)  oacc[18 + j] = 2.0f / (1.0f + expf(-oacc[18 + j]));
    auto GATHER = [&](int kk2, float* sarr) {
        const int ky = kk2 / 3, kx = kk2 % 3;
        const float py = oacc[kk2 * 2] + (float)(h - 1 + ky);
        const float px = oacc[kk2 * 2 + 1] + (float)(w - 1 + kx);
        const float m = oacc[18 + kk2];
        const float y0f = floorf(py), x0f = floorf(px);
        const float dy = py - y0f, dx = px - x0f;
        const int y0 = (int)y0f, x0 = (int)x0f, y1 = y0 + 1, x1 = x0 + 1;
        const bool vy0 = (y0 >= 0) & (y0 < H_), vy1 = (y1 >= 0) & (y1 < H_);
        const bool vx0 = (x0 >= 0) & (x0 < W_), vx1 = (x1 >= 0) & (x1 < W_);
        const float wm00 = (vy0 & vx0) ? (1.0f - dy) * (1.0f - dx) * m : 0.0f;
        const float wm01 = (vy0 & vx1) ? (1.0f - dy) * dx * m : 0.0f;
        const float wm10 = (vy1 & vx0) ? dy * (1.0f - dx) * m : 0.0f;
        const float wm11 = (vy1 & vx1) ? dy * dx * m : 0.0f;
        const int y0c = min(max(y0, 0), H_ - 1), y1c = min(max(y1, 0), H_ - 1);
        const int x0c = min(max(x0, 0), W_ - 1), x1c = min(max(x1, 0), W_ - 1);
        const int i00 = y0c * W_ + x0c, i01 = y0c * W_ + x1c;
        const int i10 = y1c * W_ + x0c, i11 = y1c * W_ + x1c;
        #pragma unroll
        for (int c4 = 0; c4 < C_; c4 += 4)
            #pragma unroll
            for (int u = 0; u < 4; ++u) {
                const float* xc = xb + (c4 + u) * HW_;
                sarr[c4 + u] = wm00 * xc[i00] + wm01 * xc[i01]
                             + wm10 * xc[i10] + wm11 * xc[i11];
            }
    };
    auto WSTAGE = [&](int kk2, s16x8* wv) {
        #pragma unroll
        for (int i = 0; i < 2; ++i) {
            const int v = i * NTF_ + tid;
            const int kg = v >> 6, o = v & 63;
            s16x8 t;
            #pragma unroll
            for (int j = 0; j < 8; ++j)
                t[j] = bf16b(w_reg[(o * C_ + kg * 8 + j) * 9 + kk2]);
            wv[i] = t;
        }
    };
    auto PACK = [&](int buf, const float* sarr, const s16x8* wv) {
        #pragma unroll
        for (int kg = 0; kg < 4; ++kg) {
            s16x8 v;
            #pragma unroll
            for (int j = 0; j < 8; ++j) v[j] = bf16b(sarr[kg * 8 + j]);
            *(s16x8*)&Sl[buf][kg][tid][0] = v;
        }
        #pragma unroll
        for (int i = 0; i < 2; ++i) {
            const int v = i * NTF_ + tid;
            const int kg = v >> 6, o = v & 63;
            *(s16x8*)&Wl[buf][kg][o][0] = wv[i];
        }
    };
    { float s0[C_]; s16x8 wv0[2]; GATHER(0, s0); WSTAGE(0, wv0); PACK(0, s0, wv0); }
    __syncthreads();
    const int lane = tid & 63, wid = tid >> 6, fr = lane & 15, fq = lane >> 4;
    f32x4 acc[4][4];
    #pragma unroll
    for (int ot = 0; ot < 4; ++ot)
        #pragma unroll
        for (int pt = 0; pt < 4; ++pt) acc[ot][pt] = (f32x4){0.f,0.f,0.f,0.f};
    #pragma unroll
    for (int kk = 0; kk < KK_; ++kk) {
        const int cur = kk & 1, nxt = cur ^ 1;
        s16x8 af[4], bfg[4];
        #pragma unroll
        for (int ot = 0; ot < 4; ++ot) af[ot] = *(const s16x8*)&Wl[cur][fq][ot*16+fr][0];
        #pragma unroll
        for (int pt = 0; pt < 4; ++pt) bfg[pt] = *(const s16x8*)&Sl[cur][fq][wid*64+pt*16+fr][0];
        float sn[C_]; s16x8 wvn[2];
        if (kk + 1 < KK_) { GATHER(kk + 1, sn); WSTAGE(kk + 1, wvn); }
        #pragma unroll
        for (int ot = 0; ot < 4; ++ot)
            #pragma unroll
            for (int pt = 0; pt < 4; ++pt)
                acc[ot][pt] = __builtin_amdgcn_mfma_f32_16x16x32_bf16(af[ot], bfg[pt], acc[ot][pt], 0, 0, 0);
        if (kk + 1 < KK_) { PACK(nxt, sn, wvn); __syncthreads(); }
    }
    float* outb = out + (size_t)bidx * (CO_ * HW_) + hwbase;
    #pragma unroll
    for (int ot = 0; ot < 4; ++ot)
        #pragma unroll
        for (int j = 0; j < 4; ++j) {
            const int o = ot * 16 + fq * 4 + j;
            float* row = outb + o * HW_ + wid * 64 + fr;
            #pragma unroll
            for (int pt = 0; pt < 4; ++pt) row[pt * 16] = acc[ot][pt][j];
        }
}

extern "C" void kernel_launch(void* const* d_in, const int* in_sizes, int n_in,
                              void* d_out, int out_size, void* d_ws, size_t ws_size,
                              hipStream_t stream) {
    const float* x     = (const float*)d_in[0];
    const float* w_off = (const float*)d_in[1];
    const float* b_off = (const float*)d_in[2];
    const float* w_mod = (const float*)d_in[3];
    const float* b_mod = (const float*)d_in[4];
    const float* w_reg = (const float*)d_in[5];
    float* out = (float*)d_out;

    const size_t WOF_OFFS  = 36864;                                  // 36 KB
    const size_t OFF_OFFS  = 65536;
    const size_t OFF_BYTES = (size_t)B_ * 27 * HW_ * sizeof(float);  // 14.2 MB
    const size_t XT_OFFS   = OFF_OFFS + OFF_BYTES;                   // 16B-aligned
    const size_t XT_BYTES  = (size_t)B_ * HW_ * C_ * sizeof(short);  // 8.4 MB

    if (ws_size >= XT_OFFS + XT_BYTES) {
        short* wb  = (short*)d_ws;
        short* wof = (short*)((char*)d_ws + WOF_OFFS);
        float* OFF = (float*)((char*)d_ws + OFF_OFFS);
        short* xtp = (short*)((char*)d_ws + XT_OFFS);
        prep_w  <<<(9 * 4 * 64 * 8) / 256, 256, 0, stream>>>(w_reg, wb);
        prep_wof<<<(9 * 4 * 32 * 8) / 256, 256, 0, stream>>>(w_off, w_mod, wof);
        prep_xt <<<B_ * HW_ / 256, 256, 0, stream>>>(x, xtp);
        offsets_mfma<<<B_ * HW_ / 64, 256, 0, stream>>>(xtp, b_off, b_mod, wof, OFF);
        dconv_main  <<<B_ * HW_ / 64, 256, 0, stream>>>(xtp, OFF, wb, out);
    } else {
        dconv_fallback<<<B_ * HW_ / TPF_, NTF_, 0, stream>>>(
            x, w_off, b_off, w_mod, b_mod, w_reg, out);
    }
}

// Round 11
// 57.063 us; speedup vs baseline: 4.9345x; 1.1625x over previous
//
#include <hip/hip_runtime.h>
#include <hip/hip_bf16.h>

#define B_  8
#define C_  32
#define H_  128
#define W_  128
#define CO_ 64
#define KK_ 9
#define HW_ (H_*W_)

typedef short s16x8 __attribute__((ext_vector_type(8)));   // 8 bf16 operand
typedef float f32x4 __attribute__((ext_vector_type(4)));   // MFMA accumulator

__device__ __forceinline__ short bf16b(float f) {
    __hip_bfloat16 h = __float2bfloat16(f);
    return __builtin_bit_cast(short, h);
}
__device__ __forceinline__ float bf2f(short s) {
    unsigned u = ((unsigned)(unsigned short)s) << 16;
    return __builtin_bit_cast(float, u);
}

// ---------------------------------------------------------------------------
// Prep (single launch, blockIdx-range dispatch):
//   blocks [0,512):   x f32[img][32][HW] -> xt bf16[img][HW][32] (transpose)
//   blocks [512,584): w_reg -> bf16 A-frag wb[kk][kg][o(64)][j]
//   blocks [584,620): w_off||w_mod||0 -> bf16 A-frag wof[kk][kg][row(32)][j]
// ---------------------------------------------------------------------------
__global__ __launch_bounds__(256) void prep_all(
    const float* __restrict__ x,
    const float* __restrict__ w_reg,
    const float* __restrict__ w_off,
    const float* __restrict__ w_mod,
    short* __restrict__ xt,
    short* __restrict__ wb,
    short* __restrict__ wof)
{
    const int bid = blockIdx.x;
    const int tid = threadIdx.x;
    if (bid < 512) {                       // ---- xt transpose
        const int img = bid & 7;
        const int pix = (bid >> 3) * 256 + tid;
        const float* xb = x + img * (C_ * HW_);
        short v[C_];
        #pragma unroll
        for (int c = 0; c < C_; ++c) v[c] = bf16b(xb[c * HW_ + pix]);
        short* dst = xt + ((size_t)img * HW_ + pix) * C_;
        #pragma unroll
        for (int q = 0; q < 4; ++q)
            *(s16x8*)(dst + q * 8) = *(s16x8*)&v[q * 8];
    } else if (bid < 512 + 72) {           // ---- wb (18432 elements)
        const int idx = (bid - 512) * 256 + tid;
        const int j  = idx & 7;
        const int o  = (idx >> 3) & 63;
        const int kg = (idx >> 9) & 3;
        const int kk = idx >> 11;
        wb[idx] = bf16b(w_reg[(o * C_ + kg * 8 + j) * 9 + kk]);
    } else {                               // ---- wof (9216 elements)
        const int idx = (bid - 584) * 256 + tid;
        const int j   = idx & 7;
        const int row = (idx >> 3) & 31;
        const int kg  = (idx >> 8) & 3;
        const int kk  = idx >> 10;
        const int c   = kg * 8 + j;
        float v = 0.0f;
        if (row < 18)      v = w_off[(row * C_ + c) * 9 + kk];
        else if (row < 27) v = w_mod[((row - 18) * C_ + c) * 9 + kk];
        wof[idx] = bf16b(v);
    }
}

// ---------------------------------------------------------------------------
// Fused: stage-1 conv (MFMA) -> LDS offset exchange -> gather + MFMA einsum.
// Block = 4 waves x 16 pixels = 64 pixels. Phase 1: per tap ONE 16B B-frag
// load from xt + 2 MFMA; D-frag (27 rows x 16 px) -> OFFl via LDS. Phase 2:
// per kk: 3 LDS offset reads, 4x16B taps, VALU bilinear, 4 MFMA.
// ---------------------------------------------------------------------------
__global__ __launch_bounds__(256, 4) void dconv_fused2(
    const short* __restrict__ xt,
    const float* __restrict__ b_off,
    const float* __restrict__ b_mod,
    const short* __restrict__ wof,
    const short* __restrict__ wb,
    float* __restrict__ out)
{
    __shared__ float OFFl[27][72];      // 72 = 64 + pad (bank spread), 7.8 KB

    const int tid  = threadIdx.x;
    const int lane = tid & 63;
    const int wid  = tid >> 6;
    const int fr   = lane & 15;         // pixel within wave slice
    const int fq   = lane >> 4;         // channel group
    const int img  = blockIdx.x & 7;    // image == XCD
    const int hwbase = (blockIdx.x >> 3) * 64 + wid * 16;
    const int hw = hwbase + fr;
    const int h  = hw / W_;
    const int w  = hw % W_;
    const short* xtb = xt + (size_t)img * HW_ * C_;
    const s16x8* wofv = (const s16x8*)wof;
    const s16x8* wbv  = (const s16x8*)wb;
    const int col = wid * 16 + fr;      // my pixel's column in OFFl

    // ---------------- phase 1: offsets/mask via MFMA -----------------------
    {
        f32x4 oa0 = (f32x4){0.f, 0.f, 0.f, 0.f};
        f32x4 oa1 = (f32x4){0.f, 0.f, 0.f, 0.f};
        const s16x8 zf = (s16x8){0,0,0,0,0,0,0,0};

        #pragma unroll
        for (int t = 0; t < 9; ++t) {
            const int yy = h + t / 3 - 1;
            const int xx = w + t % 3 - 1;
            const bool ok = (yy >= 0) & (yy < H_) & (xx >= 0) & (xx < W_);
            const int idx = yy * W_ + xx;
            const s16x8 bfrag = ok ? *(const s16x8*)&xtb[idx * C_ + fq * 8] : zf;
            const s16x8 af0 = wofv[(t * 4 + fq) * 32 + fr];
            const s16x8 af1 = wofv[(t * 4 + fq) * 32 + 16 + fr];
            oa0 = __builtin_amdgcn_mfma_f32_16x16x32_bf16(af0, bfrag, oa0, 0, 0, 0);
            oa1 = __builtin_amdgcn_mfma_f32_16x16x32_bf16(af1, bfrag, oa1, 0, 0, 0);
        }
        // D lane l: row o = ot*16 + fq*4 + i, col = fr -> LDS
        #pragma unroll
        for (int i = 0; i < 4; ++i) {
            const int o = fq * 4 + i;                 // 0..15: offsets
            OFFl[o][col] = fminf(fmaxf(oa0[i] + b_off[o], -32.0f), 32.0f);
        }
        #pragma unroll
        for (int i = 0; i < 4; ++i) {
            const int o = 16 + fq * 4 + i;            // 16,17: off; 18..26: mask
            const float v = oa1[i];
            if (o < 18)
                OFFl[o][col] = fminf(fmaxf(v + b_off[o], -32.0f), 32.0f);
            else if (o < 27)
                OFFl[o][col] = 2.0f / (1.0f + expf(-(v + b_mod[o - 18])));
        }
    }
    __syncthreads();

    // ---------------- phase 2: gather + bilinear + einsum ------------------
    const short* xtg = xtb + fq * 8;
    f32x4 acc[4];
    #pragma unroll
    for (int ot = 0; ot < 4; ++ot) acc[ot] = (f32x4){0.f, 0.f, 0.f, 0.f};

    #pragma unroll
    for (int kk = 0; kk < KK_; ++kk) {
        const int ky = kk / 3, kx = kk % 3;
        const float offy = OFFl[2 * kk + 0][col];
        const float offx = OFFl[2 * kk + 1][col];
        const float m    = OFFl[18 + kk][col];

        const float py = offy + (float)(h - 1 + ky);
        const float px = offx + (float)(w - 1 + kx);
        const float y0f = floorf(py), x0f = floorf(px);
        const float dy = py - y0f,   dx = px - x0f;
        const int y0 = (int)y0f, x0 = (int)x0f;
        const int y1 = y0 + 1,   x1 = x0 + 1;
        const bool vy0 = (y0 >= 0) & (y0 < H_);
        const bool vy1 = (y1 >= 0) & (y1 < H_);
        const bool vx0 = (x0 >= 0) & (x0 < W_);
        const bool vx1 = (x1 >= 0) & (x1 < W_);
        const float wm00 = (vy0 & vx0) ? (1.0f - dy) * (1.0f - dx) * m : 0.0f;
        const float wm01 = (vy0 & vx1) ? (1.0f - dy) * dx * m         : 0.0f;
        const float wm10 = (vy1 & vx0) ? dy * (1.0f - dx) * m         : 0.0f;
        const float wm11 = (vy1 & vx1) ? dy * dx * m                  : 0.0f;
        const int y0c = min(max(y0, 0), H_ - 1), y1c = min(max(y1, 0), H_ - 1);
        const int x0c = min(max(x0, 0), W_ - 1), x1c = min(max(x1, 0), W_ - 1);

        // 4 taps, ONE 16B load each (8 bf16 channels, aligned)
        const s16x8 v00 = *(const s16x8*)&xtg[(y0c * W_ + x0c) * C_];
        const s16x8 v01 = *(const s16x8*)&xtg[(y0c * W_ + x1c) * C_];
        const s16x8 v10 = *(const s16x8*)&xtg[(y1c * W_ + x0c) * C_];
        const s16x8 v11 = *(const s16x8*)&xtg[(y1c * W_ + x1c) * C_];

        s16x8 bfrag;
        #pragma unroll
        for (int j = 0; j < 8; ++j) {
            const float s = wm00 * bf2f(v00[j]) + wm01 * bf2f(v01[j])
                          + wm10 * bf2f(v10[j]) + wm11 * bf2f(v11[j]);
            bfrag[j] = bf16b(s);
        }

        s16x8 af[4];
        #pragma unroll
        for (int ot = 0; ot < 4; ++ot)
            af[ot] = wbv[(kk * 4 + fq) * 64 + ot * 16 + fr];

        #pragma unroll
        for (int ot = 0; ot < 4; ++ot)
            acc[ot] = __builtin_amdgcn_mfma_f32_16x16x32_bf16(
                          af[ot], bfrag, acc[ot], 0, 0, 0);
    }

    float* outb = out + (size_t)img * (CO_ * HW_) + hwbase + fr;
    #pragma unroll
    for (int ot = 0; ot < 4; ++ot)
        #pragma unroll
        for (int i = 0; i < 4; ++i)
            outb[(ot * 16 + fq * 4 + i) * HW_] = acc[ot][i];
}

// ---------------------------------------------------------------------------
// Fallback (R5 fused kernel) if workspace is too small for the pipeline.
// ---------------------------------------------------------------------------
#define TPF_ 128
#define NTF_ 128
__global__ __launch_bounds__(NTF_, 2) void dconv_fallback(
    const float* __restrict__ x, const float* __restrict__ w_off,
    const float* __restrict__ b_off, const float* __restrict__ w_mod,
    const float* __restrict__ b_mod, const float* __restrict__ w_reg,
    float* __restrict__ out)
{
    __shared__ short Sl[2][4][TPF_][8];
    __shared__ short Wl[2][4][CO_][8];
    const int tid = threadIdx.x;
    const int bidx = blockIdx.x & 7;
    const int hwbase = (blockIdx.x >> 3) * TPF_;
    const int hw = hwbase + tid;
    const int h = hw / W_, w = hw % W_;
    const float* xb = x + bidx * (C_ * HW_);
    float oacc[27];
    #pragma unroll
    for (int j = 0; j < 18; ++j) oacc[j] = b_off[j];
    #pragma unroll
    for (int j = 0; j < 9; ++j)  oacc[18 + j] = b_mod[j];
    for (int c = 0; c < C_; ++c) {
        float xv[9];
        #pragma unroll
        for (int t = 0; t < 9; ++t) {
            const int yy = h + t / 3 - 1, xx = w + t % 3 - 1;
            const bool ok = (yy >= 0) & (yy < H_) & (xx >= 0) & (xx < W_);
            xv[t] = ok ? xb[c * HW_ + yy * W_ + xx] : 0.0f;
        }
        const float* wo = w_off + c * 9;
        #pragma unroll
        for (int j = 0; j < 18; ++j)
            #pragma unroll
            for (int t = 0; t < 9; ++t)
                oacc[j] = fmaf(wo[j * (C_ * 9) + t], xv[t], oacc[j]);
        const float* wm = w_mod + c * 9;
        #pragma unroll
        for (int j = 0; j < 9; ++j)
            #pragma unroll
            for (int t = 0; t < 9; ++t)
                oacc[18 + j] = fmaf(wm[j * (C_ * 9) + t], xv[t], oacc[18 + j]);
    }
    #pragma unroll
    for (int j = 0; j < 18; ++j) oacc[j] = fminf(fmaxf(oacc[j], -32.0f), 32.0f);
    #pragma unroll
    for (int j = 0; j < 9; ++j)  oacc[18 + j] = 2.0f / (1.0f + expf(-oacc[18 + j]));
    auto GATHER = [&](int kk2, float* sarr) {
        const int ky = kk2 / 3, kx = kk2 % 3;
        const float py = oacc[kk2 * 2] + (float)(h - 1 + ky);
        const float px = oacc[kk2 * 2 + 1] + (float)(w - 1 + kx);
        const float m = oacc[18 + kk2];
        const float y0f = floorf(py), x0f = floorf(px);
        const float dy = py - y0f, dx = px - x0f;
        const int y0 = (int)y0f, x0 = (int)x0f, y1 = y0 + 1, x1 = x0 + 1;
        const bool vy0 = (y0 >= 0) & (y0 < H_), vy1 = (y1 >= 0) & (y1 < H_);
        const bool vx0 = (x0 >= 0) & (x0 < W_), vx1 = (x1 >= 0) & (x1 < W_);
        const float wm00 = (vy0 & vx0) ? (1.0f - dy) * (1.0f - dx) * m : 0.0f;
        const float wm01 = (vy0 & vx1) ? (1.0f - dy) * dx * m : 0.0f;
        const float wm10 = (vy1 & vx0) ? dy * (1.0f - dx) * m : 0.0f;
        const float wm11 = (vy1 & vx1) ? dy * dx * m : 0.0f;
        const int y0c = min(max(y0, 0), H_ - 1), y1c = min(max(y1, 0), H_ - 1);
        const int x0c = min(max(x0, 0), W_ - 1), x1c = min(max(x1, 0), W_ - 1);
        const int i00 = y0c * W_ + x0c, i01 = y0c * W_ + x1c;
        const int i10 = y1c * W_ + x0c, i11 = y1c * W_ + x1c;
        #pragma unroll
        for (int c4 = 0; c4 < C_; c4 += 4)
            #pragma unroll
            for (int u = 0; u < 4; ++u) {
                const float* xc = xb + (c4 + u) * HW_;
                sarr[c4 + u] = wm00 * xc[i00] + wm01 * xc[i01]
                             + wm10 * xc[i10] + wm11 * xc[i11];
            }
    };
    auto WSTAGE = [&](int kk2, s16x8* wv) {
        #pragma unroll
        for (int i = 0; i < 2; ++i) {
            const int v = i * NTF_ + tid;
            const int kg = v >> 6, o = v & 63;
            s16x8 t;
            #pragma unroll
            for (int j = 0; j < 8; ++j)
                t[j] = bf16b(w_reg[(o * C_ + kg * 8 + j) * 9 + kk2]);
            wv[i] = t;
        }
    };
    auto PACK = [&](int buf, const float* sarr, const s16x8* wv) {
        #pragma unroll
        for (int kg = 0; kg < 4; ++kg) {
            s16x8 v;
            #pragma unroll
            for (int j = 0; j < 8; ++j) v[j] = bf16b(sarr[kg * 8 + j]);
            *(s16x8*)&Sl[buf][kg][tid][0] = v;
        }
        #pragma unroll
        for (int i = 0; i < 2; ++i) {
            const int v = i * NTF_ + tid;
            const int kg = v >> 6, o = v & 63;
            *(s16x8*)&Wl[buf][kg][o][0] = wv[i];
        }
    };
    { float s0[C_]; s16x8 wv0[2]; GATHER(0, s0); WSTAGE(0, wv0); PACK(0, s0, wv0); }
    __syncthreads();
    const int lane = tid & 63, wid = tid >> 6, fr = lane & 15, fq = lane >> 4;
    f32x4 acc[4][4];
    #pragma unroll
    for (int ot = 0; ot < 4; ++ot)
        #pragma unroll
        for (int pt = 0; pt < 4; ++pt) acc[ot][pt] = (f32x4){0.f,0.f,0.f,0.f};
    #pragma unroll
    for (int kk = 0; kk < KK_; ++kk) {
        const int cur = kk & 1, nxt = cur ^ 1;
        s16x8 af[4], bfg[4];
        #pragma unroll
        for (int ot = 0; ot < 4; ++ot) af[ot] = *(const s16x8*)&Wl[cur][fq][ot*16+fr][0];
        #pragma unroll
        for (int pt = 0; pt < 4; ++pt) bfg[pt] = *(const s16x8*)&Sl[cur][fq][wid*64+pt*16+fr][0];
        float sn[C_]; s16x8 wvn[2];
        if (kk + 1 < KK_) { GATHER(kk + 1, sn); WSTAGE(kk + 1, wvn); }
        #pragma unroll
        for (int ot = 0; ot < 4; ++ot)
            #pragma unroll
            for (int pt = 0; pt < 4; ++pt)
                acc[ot][pt] = __builtin_amdgcn_mfma_f32_16x16x32_bf16(af[ot], bfg[pt], acc[ot][pt], 0, 0, 0);
        if (kk + 1 < KK_) { PACK(nxt, sn, wvn); __syncthreads(); }
    }
    float* outb = out + (size_t)bidx * (CO_ * HW_) + hwbase;
    #pragma unroll
    for (int ot = 0; ot < 4; ++ot)
        #pragma unroll
        for (int j = 0; j < 4; ++j) {
            const int o = ot * 16 + fq * 4 + j;
            float* row = outb + o * HW_ + wid * 64 + fr;
            #pragma unroll
            for (int pt = 0; pt < 4; ++pt) row[pt * 16] = acc[ot][pt][j];
        }
}

extern "C" void kernel_launch(void* const* d_in, const int* in_sizes, int n_in,
                              void* d_out, int out_size, void* d_ws, size_t ws_size,
                              hipStream_t stream) {
    const float* x     = (const float*)d_in[0];
    const float* w_off = (const float*)d_in[1];
    const float* b_off = (const float*)d_in[2];
    const float* w_mod = (const float*)d_in[3];
    const float* b_mod = (const float*)d_in[4];
    const float* w_reg = (const float*)d_in[5];
    float* out = (float*)d_out;

    const size_t WOF_OFFS = 36864;                                  // after wb
    const size_t XT_OFFS  = 65536;
    const size_t XT_BYTES = (size_t)B_ * HW_ * C_ * sizeof(short);  // 8.4 MB

    if (ws_size >= XT_OFFS + XT_BYTES) {
        short* wb  = (short*)d_ws;
        short* wof = (short*)((char*)d_ws + WOF_OFFS);
        short* xtp = (short*)((char*)d_ws + XT_OFFS);
        prep_all<<<620, 256, 0, stream>>>(x, w_reg, w_off, w_mod, xtp, wb, wof);
        dconv_fused2<<<B_ * HW_ / 64, 256, 0, stream>>>(xtp, b_off, b_mod,
                                                        wof, wb, out);
    } else {
        dconv_fallback<<<B_ * HW_ / TPF_, NTF_, 0, stream>>>(
            x, w_off, b_off, w_mod, b_mod, w_reg, out);
    }
}